// Round 7
// baseline (93.570 us; speedup 1.0000x reference)
//
#include <hip/hip_runtime.h>
#include <math.h>

#define HW 256
#define MINNORM 1.17549435e-38f   // 2^-126, f32 min normal

// One wave (64 lanes) per batch element; lane l owns count-support j = l.
// np ref semantics (verified R4/R6): XLA-CPU f32, FTZ/DAZ, pow underflow at
// j=42 -> support lives in [0,41] forever; FTZ erosion + exact clip endpoints
// drive the death dynamics.
// R7: (1) s1=1 steps reuse the norm sum as p_z (bit-identical under FTZ),
//     (2) pg via correctly-rounded 1/den constant table (endpoint-exact),
//     (3) cd normalize via v_rcp_f32 (off the VCC-serialized IEEE-div path),
//     (4) hardware FTZ via s_setreg (token-ordered) replaces software flush.

struct InvTbl { float v[HW]; };
static constexpr InvTbl make_inv() {
    InvTbl t{};
    for (int i = 0; i < HW; ++i) t.v[i] = 1.0f / (float)(HW - i);  // CR at compile time
    return t;
}
__constant__ InvTbl INVD = make_inv();

template <int CTRL>
__device__ __forceinline__ float dpp_sra(float x) {
    // x + (x shifted toward higher lanes within each row of 16); OOB lanes add 0
    int s = __builtin_amdgcn_update_dpp(0, __builtin_bit_cast(int, x),
                                        CTRL, 0xf, 0xf, true);
    return x + __builtin_bit_cast(float, s);
}

__device__ __forceinline__ float rdlane(float x, int lane) {
    return __builtin_bit_cast(float,
        __builtin_amdgcn_readlane(__builtin_bit_cast(int, x), lane));
}

// wave64 sum, result wave-uniform: 4x DPP row_shr (CDNA-legal) + readlane combine
__device__ __forceinline__ float wave_total(float x) {
    x = dpp_sra<0x111>(x);   // row_shr:1
    x = dpp_sra<0x112>(x);   // row_shr:2
    x = dpp_sra<0x114>(x);   // row_shr:4
    x = dpp_sra<0x118>(x);   // row_shr:8  -> lanes 15/31/47/63 hold row sums
    const float a = rdlane(x, 15), b = rdlane(x, 31);
    const float c = rdlane(x, 47), d = rdlane(x, 63);
    return (a + b) + (c + d);   // nonneg terms: order only ulp-noise
}

__global__ void __launch_bounds__(64)
spair_count_kl(const float* __restrict__ z_pres,
               const float* __restrict__ z_prob,
               float* __restrict__ out) {
    // f32 denorm mode = flush in+out (FP_DENORM[1:0]=0), matching XLA FTZ.
    // Token output data-orders all downstream f32 ops after the setreg.
    float tok;
    asm volatile("s_setreg_imm32_b32 hwreg(HW_REG_MODE, 4, 2), 0\n\t"
                 "v_mov_b32 %0, 0" : "=v"(tok));

    const int lane = threadIdx.x;   // 0..63
    const int b = blockIdx.x;       // batch element

    // ---- cd0 init (unchanged from passing R4/R6): support cap j=41 ----
    const float e2f = (float)exp(2.0);                    // f32(exp(2))
    const float pf  = (float)(1.0 / ((double)e2f + 1.0)); // p in f32
    const double pd = (double)pf;
    const double l2p = log2(pd);
    float cd = 0.0f;
    if (lane <= 41) {
        const double powj = exp2((double)lane * l2p);      // accurate p^j
        float v = (float)((1.0 - pd) * powj);              // (1-p)*p^j, f32
        cd = (v < MINNORM) ? 0.0f : v;                     // j=41 survives (1.006*2^-126)
    }
    {
        float s = cd;
#pragma unroll
        for (int off = 32; off > 0; off >>= 1) s += __shfl_xor(s, off, 64);
        cd = cd / s;
    }
    cd += tok;                 // order the recurrence after the setreg
    const float jf = (float)lane;
    float csf = tok;           // 0.0f, ordered

    const float* presb = z_pres + (size_t)b * HW;
    const float* probb = z_prob + (size_t)b * HW;
    float* outb = out + (size_t)b * HW;

#pragma unroll 1
    for (int k = 0; k < 4; ++k) {
        const float myprob = probb[k * 64 + lane];
        const float mypres = presb[k * 64 + lane];
        // sample = round(z_pres) in {0,1}; rintf = round-half-even = np.round
        const unsigned long long smask = __ballot(rintf(mypres) != 0.0f);
        float my_pz = 0.0f;

#pragma unroll 2
        for (int ii = 0; ii < 64; ++ii) {
            const int i = k * 64 + ii;
            const float fden = (float)(HW - i);
            const float inv = INVD.v[i];            // SMEM uniform load, CR 1/den
            const bool s1 = ((smask >> ii) & 1ULL) != 0ULL;   // wave-uniform

            // pg = clip(j-csf,0,den)/den; endpoints exact: t==0 -> 0 (mul),
            // t==den -> forced 1.0 (den*inv may not round to 1).
            float t = fminf(fmaxf(jf - csf, 0.0f), fden);
            float pg = (t == fden) ? 1.0f : t * inv;

            float pz;
            if (s1) {
                // mult == pg: ref's p_z terms ftz(cd*pg) ARE the norm terms.
                const float prodm = cd * pg;            // HW-FTZ flushes denorms
                const float p2 = wave_total(prodm);     // pre-clamp sum == p_z
                pz = p2;
                const float norm = fmaxf(p2, 1e-6f);
                cd = prodm * __builtin_amdgcn_rcpf(norm);
                csf += 1.0f;
            } else {
                const float mult = 1.0f - pg;
                const float prodm = cd * mult;          // HW-FTZ
                const float p1 = cd * pg;               // HW-FTZ (matches ref)
                const float p2 = wave_total(prodm);     // on-chain
                pz = wave_total(p1);                    // off-chain
                const float norm = fmaxf(p2, 1e-6f);
                cd = prodm * __builtin_amdgcn_rcpf(norm);
            }

            my_pz = (ii == lane) ? pz : my_pz;   // wave-uniform p_z for step i
        }

        // KL for this lane's step (i = k*64 + lane)
        const float prob = myprob;
        const float pz = my_pz;
        const float kl = prob * (logf(prob + 1e-9f) - logf(pz + 1e-9f))
                       + (1.0f - prob) * (logf((1.0f - prob) + 1e-9f)
                                        - logf((1.0f - pz) + 1e-9f));
        outb[k * 64 + lane] = kl;   // coalesced across the wave
    }
}

extern "C" void kernel_launch(void* const* d_in, const int* in_sizes, int n_in,
                              void* d_out, int out_size, void* d_ws, size_t ws_size,
                              hipStream_t stream) {
    const float* z_pres = (const float*)d_in[0];      // setup_inputs order
    const float* z_prob = (const float*)d_in[1];
    float* out = (float*)d_out;
    const int nbatch = in_sizes[0] / HW;              // 1024
    spair_count_kl<<<dim3(nbatch), dim3(64), 0, stream>>>(z_pres, z_prob, out);
}

// Round 8
// 74.565 us; speedup vs baseline: 1.2549x; 1.2549x over previous
//
#include <hip/hip_runtime.h>
#include <math.h>

#define HW 256
#define MINNORM 1.17549435e-38f   // 2^-126, f32 min normal

// One wave (64 lanes) per batch element; lane l owns count-support j = l.
// np ref semantics (verified R4/R6/R7): XLA-CPU f32, FTZ/DAZ, pow underflow at
// j=42 -> support lives in [0,41] forever.
// R8: (1) death short-circuit — first step with norm-presum == 0.0f exactly is
//     absorbing (cd==0, p_z==0 forever); tail KL = epilogue with my_pz=0,
//     bit-identical to running the scan. Cuts ~256 -> ~110 executed steps.
//     (2) 1/den via init-time IEEE divides + v_readlane (no s_load on chain).
//     (3) reduction drops row 3 (lanes 48-63 structurally zero — bit-exact).

template <int CTRL>
__device__ __forceinline__ float dpp_sra(float x) {
    // x + (x shifted toward higher lanes within each row of 16); OOB lanes add 0
    int s = __builtin_amdgcn_update_dpp(0, __builtin_bit_cast(int, x),
                                        CTRL, 0xf, 0xf, true);
    return x + __builtin_bit_cast(float, s);
}

__device__ __forceinline__ float rdlane(float x, int l) {
    return __builtin_bit_cast(float,
        __builtin_amdgcn_readlane(__builtin_bit_cast(int, x), l));
}

// wave sum (support lives in lanes 0..47; row 3 is exactly 0 forever)
__device__ __forceinline__ float wave_total(float x) {
    x = dpp_sra<0x111>(x);   // row_shr:1
    x = dpp_sra<0x112>(x);   // row_shr:2
    x = dpp_sra<0x114>(x);   // row_shr:4
    x = dpp_sra<0x118>(x);   // row_shr:8  -> lanes 15/31/47 hold row sums
    const float a = rdlane(x, 15), b = rdlane(x, 31), c = rdlane(x, 47);
    return (a + b) + c;      // + row3(=0) dropped: bit-exact
}

__global__ void __launch_bounds__(64)
spair_count_kl(const float* __restrict__ z_pres,
               const float* __restrict__ z_prob,
               float* __restrict__ out) {
    // f32 denorm mode = flush in+out (FP_DENORM[1:0]=0), matching XLA FTZ.
    float tok;
    asm volatile("s_setreg_imm32_b32 hwreg(HW_REG_MODE, 4, 2), 0\n\t"
                 "v_mov_b32 %0, 0" : "=v"(tok));

    const int lane = threadIdx.x;   // 0..63
    const int b = blockIdx.x;       // batch element

    // ---- cd0 init (unchanged from passing R4/R6/R7): support cap j=41 ----
    const float e2f = (float)exp(2.0);                    // f32(exp(2))
    const float pf  = (float)(1.0 / ((double)e2f + 1.0)); // p in f32
    const double pd = (double)pf;
    const double l2p = log2(pd);
    float cd = 0.0f;
    if (lane <= 41) {
        const double powj = exp2((double)lane * l2p);      // accurate p^j
        float v = (float)((1.0 - pd) * powj);              // (1-p)*p^j, f32
        cd = (v < MINNORM) ? 0.0f : v;                     // j=41 survives
    }
    {
        float s = cd;
#pragma unroll
        for (int off = 32; off > 0; off >>= 1) s += __shfl_xor(s, off, 64);
        cd = cd / s;
    }
    cd += tok;                 // order the recurrence after the setreg
    const float jf = (float)lane;
    float csf = tok;           // 0.0f, ordered

    // per-lane 1/den registers: it[m] = CR 1/(256 - (m*64+lane)) (IEEE divide)
    float it0 = 1.0f / (float)(HW - lane);
    float it1 = 1.0f / (float)(HW - 64 - lane);
    float it2 = 1.0f / (float)(HW - 128 - lane);
    float it3 = 1.0f / (float)(HW - 192 - lane);

    const float* presb = z_pres + (size_t)b * HW;
    const float* probb = z_prob + (size_t)b * HW;
    float* outb = out + (size_t)b * HW;

    bool dead = false;

#pragma unroll 1
    for (int k = 0; k < 4; ++k) {
        const float myprob = probb[k * 64 + lane];
        const float mypres = presb[k * 64 + lane];
        // sample = round(z_pres) in {0,1}; rintf = round-half-even = np.round
        const unsigned long long smask = __ballot(rintf(mypres) != 0.0f);
        float my_pz = 0.0f;
        const float itk = (k == 0) ? it0 : (k == 1) ? it1 : (k == 2) ? it2 : it3;

        if (!dead) {
#pragma unroll 4
            for (int ii = 0; ii < 64; ++ii) {
                const int i = k * 64 + ii;
                const float fden = (float)(HW - i);
                const float inv = rdlane(itk, ii);        // CR 1/den, off-chain
                const bool s1 = ((smask >> ii) & 1ULL) != 0ULL;  // wave-uniform

                // pg = clip(j-csf,0,den)/den; endpoints exact (0 via mul, 1 forced)
                float t = fminf(fmaxf(jf - csf, 0.0f), fden);
                float pg = (t == fden) ? 1.0f : t * inv;

                float pz, p2;
                if (s1) {
                    // mult == pg: ref's p_z terms ftz(cd*pg) ARE the norm terms
                    const float prodm = cd * pg;          // HW-FTZ
                    p2 = wave_total(prodm);               // pre-clamp sum == p_z
                    pz = p2;
                    const float norm = fmaxf(p2, 1e-6f);
                    cd = prodm * __builtin_amdgcn_rcpf(norm);
                    csf += 1.0f;
                } else {
                    const float mult = 1.0f - pg;
                    const float prodm = cd * mult;        // HW-FTZ
                    const float p1 = cd * pg;             // HW-FTZ
                    p2 = wave_total(prodm);               // on-chain
                    pz = wave_total(p1);                  // off-chain
                    const float norm = fmaxf(p2, 1e-6f);
                    cd = prodm * __builtin_amdgcn_rcpf(norm);
                }

                my_pz = (ii == lane) ? pz : my_pz;  // wave-uniform p_z, step i

                // Absorbing death: presum exactly 0 -> cd==0 & p_z==0 forever.
                // (Sum of non-negatives: ==0 iff all terms 0; wave-uniform.)
                if (p2 == 0.0f) { dead = true; break; }
            }
        }

        // KL for this lane's step (i = k*64 + lane); my_pz==0 for dead steps
        // evaluates the exact same expression the ref computes with p_z=0.
        const float prob = myprob;
        const float pz = my_pz;
        const float kl = prob * (logf(prob + 1e-9f) - logf(pz + 1e-9f))
                       + (1.0f - prob) * (logf((1.0f - prob) + 1e-9f)
                                        - logf((1.0f - pz) + 1e-9f));
        outb[k * 64 + lane] = kl;   // coalesced across the wave
    }
}

extern "C" void kernel_launch(void* const* d_in, const int* in_sizes, int n_in,
                              void* d_out, int out_size, void* d_ws, size_t ws_size,
                              hipStream_t stream) {
    const float* z_pres = (const float*)d_in[0];      // setup_inputs order
    const float* z_prob = (const float*)d_in[1];
    float* out = (float*)d_out;
    const int nbatch = in_sizes[0] / HW;              // 1024
    spair_count_kl<<<dim3(nbatch), dim3(64), 0, stream>>>(z_pres, z_prob, out);
}

// Round 9
// 69.356 us; speedup vs baseline: 1.3491x; 1.0751x over previous
//
#include <hip/hip_runtime.h>
#include <math.h>

#define HW 256
#define MINNORM 1.17549435e-38f   // 2^-126, f32 min normal

// One wave (64 lanes) per batch element; lane l owns count-support j = l.
// np ref semantics (verified R4/R6/R7/R8): XLA-CPU f32, FTZ/DAZ, pow underflow
// at j=42 -> support lives in [0,41] forever.
// R9: fully branchless inner step (cndmask selects; both reductions always),
//     16-step straight-line unroll, death check hoisted to sub-block boundary
//     (p2==0 is absorbing; running while dead is bit-exact, so a lazy check
//     loses nothing). Removes 3 branches/step + enables scheduling overlap.

struct InvTbl { float v[HW]; };
static constexpr InvTbl make_inv() {
    InvTbl t{};
    for (int i = 0; i < HW; ++i) t.v[i] = 1.0f / (float)(HW - i);  // CR 1/den
    return t;
}
__constant__ InvTbl INVD = make_inv();

template <int CTRL>
__device__ __forceinline__ float dpp_sra(float x) {
    // x + (x shifted toward higher lanes within each row of 16); OOB lanes add 0
    int s = __builtin_amdgcn_update_dpp(0, __builtin_bit_cast(int, x),
                                        CTRL, 0xf, 0xf, true);
    return x + __builtin_bit_cast(float, s);
}

__device__ __forceinline__ float rdlane(float x, int l) {
    return __builtin_bit_cast(float,
        __builtin_amdgcn_readlane(__builtin_bit_cast(int, x), l));
}

// wave sum (support lives in lanes 0..47; row 3 is exactly 0 forever)
__device__ __forceinline__ float wave_total(float x) {
    x = dpp_sra<0x111>(x);   // row_shr:1
    x = dpp_sra<0x112>(x);   // row_shr:2
    x = dpp_sra<0x114>(x);   // row_shr:4
    x = dpp_sra<0x118>(x);   // row_shr:8  -> lanes 15/31/47 hold row sums
    const float a = rdlane(x, 15), b = rdlane(x, 31), c = rdlane(x, 47);
    return (a + b) + c;      // row3(=0) dropped: bit-exact
}

__global__ void __launch_bounds__(64)
spair_count_kl(const float* __restrict__ z_pres,
               const float* __restrict__ z_prob,
               float* __restrict__ out) {
    // f32 denorm mode = flush in+out (FP_DENORM[1:0]=0), matching XLA FTZ.
    float tok;
    asm volatile("s_setreg_imm32_b32 hwreg(HW_REG_MODE, 4, 2), 0\n\t"
                 "v_mov_b32 %0, 0" : "=v"(tok));

    const int lane = threadIdx.x;   // 0..63
    const int b = blockIdx.x;       // batch element

    // ---- cd0 init (unchanged from passing R4..R8): support cap j=41 ----
    const float e2f = (float)exp(2.0);                    // f32(exp(2))
    const float pf  = (float)(1.0 / ((double)e2f + 1.0)); // p in f32
    const double pd = (double)pf;
    const double l2p = log2(pd);
    float cd = 0.0f;
    if (lane <= 41) {
        const double powj = exp2((double)lane * l2p);      // accurate p^j
        float v = (float)((1.0 - pd) * powj);              // (1-p)*p^j, f32
        cd = (v < MINNORM) ? 0.0f : v;                     // j=41 survives
    }
    {
        float s = cd;
#pragma unroll
        for (int off = 32; off > 0; off >>= 1) s += __shfl_xor(s, off, 64);
        cd = cd / s;
    }
    cd += tok;                 // order the recurrence after the setreg
    const float jf = (float)lane;
    float csf = tok;           // 0.0f, ordered

    const float* presb = z_pres + (size_t)b * HW;
    const float* probb = z_prob + (size_t)b * HW;
    float* outb = out + (size_t)b * HW;

    bool dead = false;

#pragma unroll 1
    for (int k = 0; k < 4; ++k) {
        const float myprob = probb[k * 64 + lane];
        const float mypres = presb[k * 64 + lane];
        // sample = round(z_pres) in {0,1}; rintf = round-half-even = np.round
        const unsigned long long smask = __ballot(rintf(mypres) != 0.0f);
        float my_pz = 0.0f;

        if (!dead) {
#pragma unroll 1
            for (int blk = 0; blk < 4; ++blk) {
                float p2 = 1.0f;   // last-step presum (absorbing-zero sentinel)
#pragma unroll
                for (int u = 0; u < 16; ++u) {
                    const int ii = blk * 16 + u;
                    const int i = k * 64 + ii;
                    const float fden = (float)(HW - i);     // uniform
                    const float inv = INVD.v[i];            // uniform s_load, CR 1/den
                    const bool s1 = ((smask >> ii) & 1ULL) != 0ULL; // uniform

                    // pg = clip(j-csf,0,den)/den; endpoints exact
                    // (0 via mul, 1 forced — den*inv may not round to 1)
                    const float t = fminf(fmaxf(jf - csf, 0.0f), fden);
                    const float pg = (t == fden) ? 1.0f : t * inv;
                    const float mult = s1 ? pg : (1.0f - pg);  // cndmask

                    const float prodm = cd * mult;   // HW-FTZ (state path)
                    const float p1 = cd * pg;        // HW-FTZ (p_z path)
                    p2 = wave_total(prodm);          // on-chain
                    const float p1s = wave_total(p1);// off-chain
                    const float pz = s1 ? p2 : p1s;  // s1: terms identical

                    const float norm = fmaxf(p2, 1e-6f);       // clip(sum,1e-6,∞)
                    cd = prodm * __builtin_amdgcn_rcpf(norm);  // off VCC-div path
                    csf += s1 ? 1.0f : 0.0f;

                    my_pz = (ii == lane) ? pz : my_pz;  // capture step-i p_z
                }
                // Lazy absorbing-death check: any earlier zero keeps p2 at 0.
                if (p2 == 0.0f) { dead = true; break; }
            }
        }

        // KL for this lane's step (i = k*64 + lane); my_pz==0 on dead steps is
        // exactly the ref's p_z=0 closed form.
        const float prob = myprob;
        const float pz = my_pz;
        const float kl = prob * (logf(prob + 1e-9f) - logf(pz + 1e-9f))
                       + (1.0f - prob) * (logf((1.0f - prob) + 1e-9f)
                                        - logf((1.0f - pz) + 1e-9f));
        outb[k * 64 + lane] = kl;   // coalesced across the wave
    }
}

extern "C" void kernel_launch(void* const* d_in, const int* in_sizes, int n_in,
                              void* d_out, int out_size, void* d_ws, size_t ws_size,
                              hipStream_t stream) {
    const float* z_pres = (const float*)d_in[0];      // setup_inputs order
    const float* z_prob = (const float*)d_in[1];
    float* out = (float*)d_out;
    const int nbatch = in_sizes[0] / HW;              // 1024
    spair_count_kl<<<dim3(nbatch), dim3(64), 0, stream>>>(z_pres, z_prob, out);
}

// Round 12
// 69.355 us; speedup vs baseline: 1.3492x; 1.0000x over previous
//
#include <hip/hip_runtime.h>
#include <math.h>

#define HW 256
#define MINNORM 1.17549435e-38f   // 2^-126, f32 min normal

// One wave (64 lanes) per batch element; lane l owns count-support j = l.
// np ref semantics (verified R4..R9): XLA-CPU f32, FTZ/DAZ, pow underflow at
// j=42 -> support lives in [0,41].
// HARD-WON:
//  R10: death timing rides on per-step renormalized FTZ erosion — state path
//       must replicate flush+normalize op-for-op each step (ulp noise OK,
//       threshold-scale noise NOT).
//  R11: 0-sample p_z via S-p2 is catastrophic cancellation near death -> NaN.
//       Output p_z needs a direct nonneg-sum reduction (no cancellation).
// R12 = R9 numerics bit-identical; scheduling-only: fused dual reduction
//       (interleaved DPP stages hide each other's hazard waits), 1/den from
//       per-lane registers + readlane (no s_load in hot loop), launch_bounds
//       (64,1) so the allocator doesn't starve ILP (R9 ran at 12 VGPRs).

template <int CTRL>
__device__ __forceinline__ float dpp_sra(float x) {
    // x + (x shifted toward higher lanes within each row of 16); OOB lanes add 0
    int s = __builtin_amdgcn_update_dpp(0, __builtin_bit_cast(int, x),
                                        CTRL, 0xf, 0xf, true);
    return x + __builtin_bit_cast(float, s);
}

__device__ __forceinline__ float rdlane(float x, int l) {
    return __builtin_bit_cast(float,
        __builtin_amdgcn_readlane(__builtin_bit_cast(int, x), l));
}

// Dual wave sum, stages interleaved (independent chains hide each other's
// VALU->DPP and VALU->readlane wait states). Support lives in lanes 0..41;
// row 3 structurally zero -> dropped (bit-exact). sx add order == R9.
__device__ __forceinline__ void wave_total2(float x, float y,
                                            float& sx, float& sy) {
    x = dpp_sra<0x111>(x);  y = dpp_sra<0x111>(y);
    x = dpp_sra<0x112>(x);  y = dpp_sra<0x112>(y);
    x = dpp_sra<0x114>(x);  y = dpp_sra<0x114>(y);
    x = dpp_sra<0x118>(x);  y = dpp_sra<0x118>(y);
    const float a0 = rdlane(x, 15), b0 = rdlane(y, 15);
    const float a1 = rdlane(x, 31), b1 = rdlane(y, 31);
    const float a2 = rdlane(x, 47), b2 = rdlane(y, 47);
    sx = (a0 + a1) + a2;
    sy = (b0 + b1) + b2;
}

__global__ void __launch_bounds__(64, 1)
spair_count_kl(const float* __restrict__ z_pres,
               const float* __restrict__ z_prob,
               float* __restrict__ out) {
    // f32 denorm mode = flush in+out (FP_DENORM[1:0]=0), matching XLA FTZ.
    float tok;
    asm volatile("s_setreg_imm32_b32 hwreg(HW_REG_MODE, 4, 2), 0\n\t"
                 "v_mov_b32 %0, 0" : "=v"(tok));

    const int lane = threadIdx.x;   // 0..63
    const int b = blockIdx.x;       // batch element

    // ---- cd0 init (unchanged from passing R4..R9): support cap j=41 ----
    const float e2f = (float)exp(2.0);                    // f32(exp(2))
    const float pf  = (float)(1.0 / ((double)e2f + 1.0)); // p in f32
    const double pd = (double)pf;
    const double l2p = log2(pd);
    float cd = 0.0f;
    if (lane <= 41) {
        const double powj = exp2((double)lane * l2p);      // accurate p^j
        float v = (float)((1.0 - pd) * powj);              // (1-p)*p^j, f32
        cd = (v < MINNORM) ? 0.0f : v;                     // j=41 survives
    }
    {
        float s = cd;
#pragma unroll
        for (int off = 32; off > 0; off >>= 1) s += __shfl_xor(s, off, 64);
        cd = cd / s;
    }
    cd += tok;                 // order the recurrence after the setreg
    const float jf = (float)lane;
    float csf = tok;           // 0.0f, ordered

    // per-lane CR 1/den registers (bit-identical to 1.0f/(float)(HW-i)):
    const float it0 = 1.0f / (float)(HW - lane);
    const float it1 = 1.0f / (float)(HW - 64 - lane);
    const float it2 = 1.0f / (float)(HW - 128 - lane);
    const float it3 = 1.0f / (float)(HW - 192 - lane);

    const float* presb = z_pres + (size_t)b * HW;
    const float* probb = z_prob + (size_t)b * HW;
    float* outb = out + (size_t)b * HW;

    bool dead = false;

#pragma unroll 1
    for (int k = 0; k < 4; ++k) {
        const float myprob = probb[k * 64 + lane];
        const float mypres = presb[k * 64 + lane];
        // sample = round(z_pres) in {0,1}; rintf = round-half-even = np.round
        const unsigned long long smask = __ballot(rintf(mypres) != 0.0f);
        float my_pz = 0.0f;
        const float itk = (k == 0) ? it0 : (k == 1) ? it1 : (k == 2) ? it2 : it3;

        if (!dead) {
#pragma unroll 1
            for (int blk = 0; blk < 4; ++blk) {
                float p2 = 1.0f;   // last-step presum (absorbing-zero sentinel)
#pragma unroll
                for (int u = 0; u < 16; ++u) {
                    const int ii = blk * 16 + u;
                    const int i = k * 64 + ii;
                    const float fden = (float)(HW - i);     // uniform
                    const float inv = rdlane(itk, ii);      // CR 1/den, off-chain
                    const bool s1 = ((smask >> ii) & 1ULL) != 0ULL; // uniform

                    // pg = clip(j-csf,0,den)/den; endpoints exact
                    // (0 via mul, 1 forced — den*inv may not round to 1)
                    const float t = fminf(fmaxf(jf - csf, 0.0f), fden);
                    const float pg = (t == fden) ? 1.0f : t * inv;
                    const float mult = s1 ? pg : (1.0f - pg);  // cndmask

                    // ---- STATE PATH (bit-identical to R9) ----
                    const float prodm = cd * mult;       // HW-FTZ
                    const float p1 = cd * pg;            // HW-FTZ (p_z terms)
                    float p1s;
                    wave_total2(prodm, p1, p2, p1s);     // fused dual reduction
                    const float norm = fmaxf(p2, 1e-6f); // clip(sum,1e-6,∞)
                    const float invn = __builtin_amdgcn_rcpf(norm);
                    cd = prodm * invn;                   // renormalize
                    csf += s1 ? 1.0f : 0.0f;

                    // ---- OUTPUT PATH ----
                    // s1: ref p_z terms == norm terms exactly -> p2.
                    const float pz = s1 ? p2 : p1s;
                    my_pz = (ii == lane) ? pz : my_pz;   // capture step-i p_z
                }
                // Lazy absorbing-death check: any earlier zero keeps p2 at 0.
                if (p2 == 0.0f) { dead = true; break; }
            }
        }

        // KL for this lane's step (i = k*64 + lane); my_pz==0 on dead steps is
        // exactly the ref's p_z=0 closed form.
        const float prob = myprob;
        const float pz = my_pz;
        const float kl = prob * (logf(prob + 1e-9f) - logf(pz + 1e-9f))
                       + (1.0f - prob) * (logf((1.0f - prob) + 1e-9f)
                                        - logf((1.0f - pz) + 1e-9f));
        outb[k * 64 + lane] = kl;   // coalesced across the wave
    }
}

extern "C" void kernel_launch(void* const* d_in, const int* in_sizes, int n_in,
                              void* d_out, int out_size, void* d_ws, size_t ws_size,
                              hipStream_t stream) {
    const float* z_pres = (const float*)d_in[0];      // setup_inputs order
    const float* z_prob = (const float*)d_in[1];
    float* out = (float*)d_out;
    const int nbatch = in_sizes[0] / HW;              // 1024
    spair_count_kl<<<dim3(nbatch), dim3(64), 0, stream>>>(z_pres, z_prob, out);
}